// Round 3
// baseline (76.678 us; speedup 1.0000x reference)
//
#include <hip/hip_runtime.h>

// out[b,m,n,p] = proj0[b,m] * proj1[b,n] * proj2[m,p]
// proj_j[b,o] = sum_i x[b,i] * w[o,i,j],  x:(96,3) w:(96,3,8)  w[o,i,j] at o*24+i*8+j
// Second matmul's batch broadcast aligns proj2's batch dim with m (not b).

#define NB 96
#define MG 8                    // m-values per block
#define GROUPS (NB / MG)        // 12

typedef float f32x4 __attribute__((ext_vector_type(4)));

__global__ __launch_bounds__(256) void nckart_kernel(
    const float* __restrict__ x,   // [96,3]
    const float* __restrict__ w,   // [96,3,8]
    float* __restrict__ out)       // [96,96,96,96] flat
{
    const int blk = blockIdx.x;          // 0..1151
    const int b   = blk / GROUPS;
    const int m0  = (blk % GROUPS) * MG;
    const int t   = threadIdx.x;

    __shared__ float p1[NB];             // proj1[b, n]
    __shared__ float sp[MG][NB];         // proj0[b,m0+ml] * proj2[m0+ml, p]

    const float xb0 = x[b*3 + 0], xb1 = x[b*3 + 1], xb2 = x[b*3 + 2];

    if (t < NB) {
        p1[t] = xb0 * w[t*24 + 1] + xb1 * w[t*24 + 9] + xb2 * w[t*24 + 17];
    }
    // 768 sp entries, 256 threads -> 3 each
    for (int e = t; e < MG * NB; e += 256) {
        const int ml = e / NB;
        const int p  = e % NB;
        const int m  = m0 + ml;
        const float s  = xb0 * w[m*24 + 0] + xb1 * w[m*24 + 8] + xb2 * w[m*24 + 16];
        const float p2 = x[m*3 + 0] * w[p*24 + 2]
                       + x[m*3 + 1] * w[p*24 + 10]
                       + x[m*3 + 2] * w[p*24 + 18];
        sp[ml][p] = s * p2;
    }
    __syncthreads();

    // Contiguous output region for this block: 8 * 96 * 96 floats = 288 KB.
    f32x4* out4 = reinterpret_cast<f32x4*>(out) + (size_t)(b * NB + m0) * (NB * NB / 4);

    #pragma unroll
    for (int ml = 0; ml < MG; ++ml) {
        const f32x4* sp4 = reinterpret_cast<const f32x4*>(sp[ml]);
        f32x4* o4 = out4 + (size_t)ml * (NB * NB / 4);
        #pragma unroll
        for (int it = 0; it < 9; ++it) {
            const int idx = t + it * 256;    // 0..2303 float4 slots in this m-tile
            const int n   = idx / 24;
            const int p4  = idx % 24;
            f32x4 v = sp4[p4];
            const float a = p1[n];
            v *= a;
            __builtin_nontemporal_store(v, &o4[idx]);
        }
    }
}

extern "C" void kernel_launch(void* const* d_in, const int* in_sizes, int n_in,
                              void* d_out, int out_size, void* d_ws, size_t ws_size,
                              hipStream_t stream) {
    const float* x = (const float*)d_in[0];
    const float* w = (const float*)d_in[1];
    float* out = (float*)d_out;

    nckart_kernel<<<NB * GROUPS, 256, 0, stream>>>(x, w, out);
}

// Round 4
// 67.893 us; speedup vs baseline: 1.1294x; 1.1294x over previous
//
#include <hip/hip_runtime.h>

// out[b,m,n,p] = proj0[b,m] * proj1[b,n] * proj2[m,p]
// proj_j[b,o] = sum_i x[b,i] * w[o,i,j],  x:(96,3) w:(96,3,8)  w[o,i,j] at o*24+i*8+j
// Second matmul's batch broadcast aligns proj2's batch dim with m (not b).

#define NB 96
#define MG 4                    // m-values per block
#define GROUPS (NB / MG)        // 24  -> grid 96*24 = 2304 = 9 blocks/CU exactly

typedef float f32x4 __attribute__((ext_vector_type(4)));

__global__ __launch_bounds__(256) void nckart_kernel(
    const float* __restrict__ x,   // [96,3]
    const float* __restrict__ w,   // [96,3,8]
    float* __restrict__ out)       // [96,96,96,96] flat
{
    const int blk = blockIdx.x;          // 0..2303
    const int b   = blk / GROUPS;
    const int m0  = (blk % GROUPS) * MG;
    const int t   = threadIdx.x;

    __shared__ float p1[NB];             // proj1[b, n]
    __shared__ float sp[MG][NB];         // proj0[b,m0+ml] * proj2[m0+ml, p]

    const float xb0 = x[b*3 + 0], xb1 = x[b*3 + 1], xb2 = x[b*3 + 2];

    if (t < NB) {
        p1[t] = xb0 * w[t*24 + 1] + xb1 * w[t*24 + 9] + xb2 * w[t*24 + 17];
    } else if (t >= 128 && t < 128 + MG * NB / 2) {
        // threads 128..319 don't exist (block=256) -> handle sp with all threads below
    }
    // 384 sp entries, 256 threads -> <=2 each
    for (int e = t; e < MG * NB; e += 256) {
        const int ml = e / NB;
        const int p  = e % NB;
        const int m  = m0 + ml;
        const float s  = xb0 * w[m*24 + 0] + xb1 * w[m*24 + 8] + xb2 * w[m*24 + 16];
        const float p2 = x[m*3 + 0] * w[p*24 + 2]
                       + x[m*3 + 1] * w[p*24 + 10]
                       + x[m*3 + 2] * w[p*24 + 18];
        sp[ml][p] = s * p2;
    }
    __syncthreads();

    // Contiguous output region for this block: 4 * 96 * 96 floats = 144 KB.
    f32x4* out4 = reinterpret_cast<f32x4*>(out) + (size_t)(b * NB + m0) * (NB * NB / 4);

    #pragma unroll
    for (int ml = 0; ml < MG; ++ml) {
        const f32x4* sp4 = reinterpret_cast<const f32x4*>(sp[ml]);
        f32x4* o4 = out4 + (size_t)ml * (NB * NB / 4);
        #pragma unroll
        for (int it = 0; it < 9; ++it) {
            const int idx = t + it * 256;    // 0..2303 float4 slots in this m-tile
            const int n   = idx / 24;
            const int p4  = idx % 24;
            f32x4 v = sp4[p4];
            const float a = p1[n];
            v *= a;
            o4[idx] = v;
        }
    }
}

extern "C" void kernel_launch(void* const* d_in, const int* in_sizes, int n_in,
                              void* d_out, int out_size, void* d_ws, size_t ws_size,
                              hipStream_t stream) {
    const float* x = (const float*)d_in[0];
    const float* w = (const float*)d_in[1];
    float* out = (float*)d_out;

    nckart_kernel<<<NB * GROUPS, 256, 0, stream>>>(x, w, out);
}